// Round 5
// baseline (45.062 us; speedup 1.0000x reference)
//
#include <hip/hip_runtime.h>
#include <math.h>

#define L_OBS   512
#define NSEG    8192
#define NB      8
#define EPS_PAR 1e-4f
#define ANG_STEP 0.012271846644580566f  // FOV / L_OBS

// New decomposition: block = (b, segchunk of 64 segs); 256 threads.
// Thread t owns beams t and t+256 (2 accumulators, no cross-lane reduce).
// One ds_read_b128 per segment serves 128 tests (2 beams x 64 lanes).
#define SCC   128                 // seg chunks
#define CSEG  (NSEG / SCC)        // 64 segments per chunk
#define PART_FLOATS  (SCC * NB * L_OBS)   // 2 MB

__global__ __launch_bounds__(256) void raycast2_kernel(
    const float4* __restrict__ seg, const float* __restrict__ pose,
    float* __restrict__ part) {
    __shared__ float4 s4[CSEG];   // {sx, sy, xd=x1-x3, yd=y1-y3}

    const int gid = blockIdx.x;   // 1024 = 8 * 128
    const int sc = gid & (SCC - 1);
    const int b  = gid >> 7;

    const float x1 = pose[b * 3 + 0];
    const float y1 = pose[b * 3 + 1];
    const float th = pose[b * 3 + 2];

    const int t = threadIdx.x;
    if (t < CSEG) {
        float4 v = seg[sc * CSEG + t];
        s4[t] = make_float4(v.z - v.x, v.w - v.y, x1 - v.x, y1 - v.y);
    }

    const float ang0 = (float)t * ANG_STEP + th;
    const float ang1 = (float)(t + 256) * ANG_STEP + th;
    const float rx0 = cosf(ang0), ry0 = sinf(ang0);
    const float rx1 = cosf(ang1), ry1 = sinf(ang1);
    const float INF = __builtin_inff();
    __syncthreads();

    float u0 = INF, u1 = INF;
    #pragma unroll 4
    for (int i = 0; i < CSEG; ++i) {
        float4 s = s4[i];                    // sx, sy, xd, yd (broadcast b128)
        float na = s.x * s.w - s.y * s.z;    // sx*yd - sy*xd (beam-independent)

        float rxs0 = s.y * rx0 - s.x * ry0;
        float nb0  = rx0 * s.w - ry0 * s.z;
        float r0   = __builtin_amdgcn_rcpf(rxs0);
        float ua0  = na  * r0;
        float ub0  = nb0 * r0;
        bool ok0 = (fabsf(rxs0) >= EPS_PAR) & (ub0 >= 0.0f) & (ub0 <= 1.0f) & (ua0 >= 0.0f);
        u0 = fminf(u0, ok0 ? ua0 : INF);

        float rxs1 = s.y * rx1 - s.x * ry1;
        float nb1  = rx1 * s.w - ry1 * s.z;
        float r1   = __builtin_amdgcn_rcpf(rxs1);
        float ua1  = na  * r1;
        float ub1  = nb1 * r1;
        bool ok1 = (fabsf(rxs1) >= EPS_PAR) & (ub1 >= 0.0f) & (ub1 <= 1.0f) & (ua1 >= 0.0f);
        u1 = fminf(u1, ok1 ? ua1 : INF);
    }

    float* __restrict__ prow = part + (size_t)sc * (NB * L_OBS) + b * L_OBS;
    prow[t]       = u0;
    prow[t + 256] = u1;
}

__global__ void finalize2_kernel(const float4* __restrict__ seg,
                                 const float* __restrict__ pose,
                                 const float* __restrict__ part,
                                 float* __restrict__ out) {
    int t = blockIdx.x * blockDim.x + threadIdx.x;
    if (t >= NB * L_OBS) return;
    const int b    = t >> 9;
    const int beam = t & (L_OBS - 1);
    const float x1 = pose[b * 3 + 0];
    const float y1 = pose[b * 3 + 1];
    const float th = pose[b * 3 + 2];
    const float ang = (float)beam * ANG_STEP + th;
    const float rx = cosf(ang), ry = sinf(ang);

    float u = INFINITY;
    #pragma unroll 8
    for (int s = 0; s < SCC; ++s) u = fminf(u, part[(size_t)s * (NB * L_OBS) + t]);

    if (isinf(u)) {
        // No valid intersection: ref takes u_a[0] (argmin of all-inf picks idx 0).
        float4 s0 = seg[0];
        float sx = s0.z - s0.x, sy = s0.w - s0.y;
        float xd = x1 - s0.x,   yd = y1 - s0.y;
        float rxs   = sy * rx - sx * ry;
        float num_a = sx * yd - sy * xd;
        u = (fabsf(rxs) < EPS_PAR) ? 0.0f : (num_a / rxs);
    }

    float ix = x1 + rx * u;
    float iy = y1 + ry * u;
    float dx = ix - x1, dy = iy - y1;
    float c = cosf(th), s = sinf(th);
    out[t * 2 + 0] = ix;
    out[t * 2 + 1] = iy;
    const int off = NB * L_OBS * 2;
    out[off + t * 2 + 0] =  dx * c + dy * s;   // R = [[c,-s],[s,c]], out = d @ R
    out[off + t * 2 + 1] = -dx * s + dy * c;
}

// ---------------- fallback path (R2, proven) if ws < 2 MB ----------------
#define SC      16
#define SEGS    (NSEG / SC)
#define PART_FLOATS_FB  (SC * NB * L_OBS)

__global__ __launch_bounds__(256) void raycast_part_kernel(
    const float4* __restrict__ seg, const float* __restrict__ pose,
    float* __restrict__ ws) {
    __shared__ float4 s4[SEGS];
    __shared__ float  sna[SEGS];
    __shared__ float  s_red[4][64];
    const int gid = blockIdx.x;
    const int sc = gid & (SC - 1);
    const int bg = (gid >> 4) & 7;
    const int b  = gid >> 7;
    const float x1 = pose[b * 3 + 0];
    const float y1 = pose[b * 3 + 1];
    const float th = pose[b * 3 + 2];
    const int tid = threadIdx.x;
    for (int i = tid; i < SEGS; i += 256) {
        float4 v = seg[sc * SEGS + i];
        float sx = v.z - v.x, sy = v.w - v.y;
        float xd = x1 - v.x, yd = y1 - v.y;
        s4[i]  = make_float4(sx, sy, xd, yd);
        sna[i] = sx * yd - sy * xd;
    }
    const int lane = tid & 63;
    const int w    = tid >> 6;
    const int beam = bg * 64 + lane;
    const float ang = (float)beam * ANG_STEP + th;
    const float rx = cosf(ang), ry = sinf(ang);
    __syncthreads();
    float umin = INFINITY;
    const float4* p  = &s4[w * 128];
    const float*  pn = &sna[w * 128];
    #pragma unroll 8
    for (int i = 0; i < 128; ++i) {
        float4 s = p[i];
        float na = pn[i];
        float rxs = s.y * rx - s.x * ry;
        float nb  = rx * s.w - ry * s.z;
        float r   = __builtin_amdgcn_rcpf(rxs);
        float ua  = na * r;
        float ub  = nb * r;
        bool ok = (fabsf(rxs) >= EPS_PAR) & (ub >= 0.0f) & (ub <= 1.0f) & (ua >= 0.0f);
        umin = fminf(umin, ok ? ua : INFINITY);
    }
    s_red[w][lane] = umin;
    __syncthreads();
    if (w == 0) {
        float m = fminf(fminf(s_red[0][lane], s_red[1][lane]),
                        fminf(s_red[2][lane], s_red[3][lane]));
        ws[sc * (NB * L_OBS) + b * L_OBS + beam] = m;
    }
}

__global__ void finalize_fb_kernel(const float4* __restrict__ seg,
                                   const float* __restrict__ pose,
                                   const float* __restrict__ part,
                                   float* __restrict__ out) {
    int t = blockIdx.x * blockDim.x + threadIdx.x;
    if (t >= NB * L_OBS) return;
    const int b    = t >> 9;
    const int beam = t & (L_OBS - 1);
    const float x1 = pose[b * 3 + 0];
    const float y1 = pose[b * 3 + 1];
    const float th = pose[b * 3 + 2];
    const float ang = (float)beam * ANG_STEP + th;
    const float rx = cosf(ang), ry = sinf(ang);
    float u = INFINITY;
    #pragma unroll
    for (int s = 0; s < SC; ++s) u = fminf(u, part[s * (NB * L_OBS) + t]);
    if (isinf(u)) {
        float4 s0 = seg[0];
        float sx = s0.z - s0.x, sy = s0.w - s0.y;
        float xd = x1 - s0.x,   yd = y1 - s0.y;
        float rxs   = sy * rx - sx * ry;
        float num_a = sx * yd - sy * xd;
        u = (fabsf(rxs) < EPS_PAR) ? 0.0f : (num_a / rxs);
    }
    float ix = x1 + rx * u;
    float iy = y1 + ry * u;
    float dx = ix - x1, dy = iy - y1;
    float c = cosf(th), s = sinf(th);
    out[t * 2 + 0] = ix;
    out[t * 2 + 1] = iy;
    const int off = NB * L_OBS * 2;
    out[off + t * 2 + 0] =  dx * c + dy * s;
    out[off + t * 2 + 1] = -dx * s + dy * c;
}

extern "C" void kernel_launch(void* const* d_in, const int* in_sizes, int n_in,
                              void* d_out, int out_size, void* d_ws, size_t ws_size,
                              hipStream_t stream) {
    const float4* seg  = (const float4*)d_in[0];   // (N,4) float32
    const float*  pose = (const float*)d_in[1];    // (B,3) float32
    float* out = (float*)d_out;

    if (ws_size >= (size_t)PART_FLOATS * sizeof(float)) {
        float* part = (float*)d_ws;                // [SCC][NB*L_OBS]
        raycast2_kernel<<<NB * SCC, 256, 0, stream>>>(seg, pose, part);
        finalize2_kernel<<<16, 256, 0, stream>>>(seg, pose, part, out);
    } else {
        float* part = (float*)d_ws;                // [SC][NB*L_OBS]
        raycast_part_kernel<<<1024, 256, 0, stream>>>(seg, pose, part);
        finalize_fb_kernel<<<16, 256, 0, stream>>>(seg, pose, part, out);
    }
}

// Round 6
// 28.589 us; speedup vs baseline: 1.5762x; 1.5762x over previous
//
#include <hip/hip_runtime.h>
#include <math.h>

#define L_OBS   512
#define NSEG    8192
#define NB      8
#define EPS_PAR 1e-4f
#define ANG_STEP 0.012271846644580566f  // FOV / L_OBS

// Main path: block = (b, beamgroup of 128 beams, segchunk of 256 segs).
// 4 waves; wave w owns segs [w*64, w*64+64); thread owns beams (bg*128+lane, +64).
// One ds_read_b128 per segment serves 128 tests; na recomputed in-loop (+2 VALU)
// so there is NO second LDS read. Partials stay small (512 KB, 32-way finalize).
#define SC2   32
#define CSEG2 (NSEG / SC2)               // 256 segs per block
#define PART2_FLOATS (SC2 * NB * L_OBS)  // 512 KB

__global__ __launch_bounds__(256) void raycast6_kernel(
    const float4* __restrict__ seg, const float* __restrict__ pose,
    float* __restrict__ part) {
    __shared__ float4 s4[CSEG2];     // {sx, sy, xd, yd}
    __shared__ float  s_red[4][128];

    const int gid = blockIdx.x;      // 1024 = 8b * 4bg * 32sc
    const int sc = gid & (SC2 - 1);
    const int bg = (gid >> 5) & 3;
    const int b  = gid >> 7;

    const float x1 = pose[b * 3 + 0];
    const float y1 = pose[b * 3 + 1];
    const float th = pose[b * 3 + 2];

    const int t = threadIdx.x;
    {
        float4 v = seg[sc * CSEG2 + t];
        s4[t] = make_float4(v.z - v.x, v.w - v.y, x1 - v.x, y1 - v.y);
    }

    const int lane = t & 63;
    const int w    = t >> 6;
    const int beam0 = bg * 128 + lane;
    const float a0 = (float)beam0 * ANG_STEP + th;
    const float a1 = (float)(beam0 + 64) * ANG_STEP + th;
    const float rx0 = cosf(a0), ry0 = sinf(a0);
    const float rx1 = cosf(a1), ry1 = sinf(a1);
    const float INF = __builtin_inff();
    __syncthreads();

    float u0 = INF, u1 = INF;
    const float4* __restrict__ p = &s4[w * 64];
    #pragma unroll 8
    for (int i = 0; i < 64; ++i) {
        float4 s = p[i];                  // broadcast b128 (only LDS op in loop)
        float na = s.x * s.w - s.y * s.z; // sx*yd - sy*xd

        float rxs0 = s.y * rx0 - s.x * ry0;
        float nb0  = rx0 * s.w - ry0 * s.z;
        float r0   = __builtin_amdgcn_rcpf(rxs0);
        float ua0  = na  * r0;
        float ub0  = nb0 * r0;
        bool ok0 = (fabsf(rxs0) >= EPS_PAR) & (ub0 >= 0.0f) & (ub0 <= 1.0f) & (ua0 >= 0.0f);
        u0 = fminf(u0, ok0 ? ua0 : INF);

        float rxs1 = s.y * rx1 - s.x * ry1;
        float nb1  = rx1 * s.w - ry1 * s.z;
        float r1   = __builtin_amdgcn_rcpf(rxs1);
        float ua1  = na  * r1;
        float ub1  = nb1 * r1;
        bool ok1 = (fabsf(rxs1) >= EPS_PAR) & (ub1 >= 0.0f) & (ub1 <= 1.0f) & (ua1 >= 0.0f);
        u1 = fminf(u1, ok1 ? ua1 : INF);
    }

    s_red[w][lane]      = u0;
    s_red[w][lane + 64] = u1;
    __syncthreads();
    if (t < 128) {
        float m = fminf(fminf(s_red[0][t], s_red[1][t]),
                        fminf(s_red[2][t], s_red[3][t]));
        part[sc * (NB * L_OBS) + b * L_OBS + bg * 128 + t] = m;
    }
}

__global__ void finalize6_kernel(const float4* __restrict__ seg,
                                 const float* __restrict__ pose,
                                 const float* __restrict__ part,
                                 float* __restrict__ out) {
    int t = blockIdx.x * blockDim.x + threadIdx.x;
    if (t >= NB * L_OBS) return;
    const int b    = t >> 9;
    const int beam = t & (L_OBS - 1);
    const float x1 = pose[b * 3 + 0];
    const float y1 = pose[b * 3 + 1];
    const float th = pose[b * 3 + 2];
    const float ang = (float)beam * ANG_STEP + th;
    const float rx = cosf(ang), ry = sinf(ang);

    float u = INFINITY;
    #pragma unroll 8
    for (int s = 0; s < SC2; ++s) u = fminf(u, part[s * (NB * L_OBS) + t]);

    if (isinf(u)) {
        // No valid intersection: ref takes u_a[0] (argmin of all-inf picks idx 0).
        float4 s0 = seg[0];
        float sx = s0.z - s0.x, sy = s0.w - s0.y;
        float xd = x1 - s0.x,   yd = y1 - s0.y;
        float rxs   = sy * rx - sx * ry;
        float num_a = sx * yd - sy * xd;
        u = (fabsf(rxs) < EPS_PAR) ? 0.0f : (num_a / rxs);
    }

    float ix = x1 + rx * u;
    float iy = y1 + ry * u;
    float dx = ix - x1, dy = iy - y1;
    float c = cosf(th), s = sinf(th);
    out[t * 2 + 0] = ix;
    out[t * 2 + 1] = iy;
    const int off = NB * L_OBS * 2;
    out[off + t * 2 + 0] =  dx * c + dy * s;   // R = [[c,-s],[s,c]], out = d @ R
    out[off + t * 2 + 1] = -dx * s + dy * c;
}

// ---------------- fallback (R2, proven) if ws < 512 KB ----------------
#define SC      16
#define SEGS    (NSEG / SC)

__global__ __launch_bounds__(256) void raycast_part_kernel(
    const float4* __restrict__ seg, const float* __restrict__ pose,
    float* __restrict__ ws) {
    __shared__ float4 s4[SEGS];
    __shared__ float  sna[SEGS];
    __shared__ float  s_red[4][64];
    const int gid = blockIdx.x;
    const int sc = gid & (SC - 1);
    const int bg = (gid >> 4) & 7;
    const int b  = gid >> 7;
    const float x1 = pose[b * 3 + 0];
    const float y1 = pose[b * 3 + 1];
    const float th = pose[b * 3 + 2];
    const int tid = threadIdx.x;
    for (int i = tid; i < SEGS; i += 256) {
        float4 v = seg[sc * SEGS + i];
        float sx = v.z - v.x, sy = v.w - v.y;
        float xd = x1 - v.x, yd = y1 - v.y;
        s4[i]  = make_float4(sx, sy, xd, yd);
        sna[i] = sx * yd - sy * xd;
    }
    const int lane = tid & 63;
    const int w    = tid >> 6;
    const int beam = bg * 64 + lane;
    const float ang = (float)beam * ANG_STEP + th;
    const float rx = cosf(ang), ry = sinf(ang);
    __syncthreads();
    float umin = INFINITY;
    const float4* p  = &s4[w * 128];
    const float*  pn = &sna[w * 128];
    #pragma unroll 8
    for (int i = 0; i < 128; ++i) {
        float4 s = p[i];
        float na = pn[i];
        float rxs = s.y * rx - s.x * ry;
        float nb  = rx * s.w - ry * s.z;
        float r   = __builtin_amdgcn_rcpf(rxs);
        float ua  = na * r;
        float ub  = nb * r;
        bool ok = (fabsf(rxs) >= EPS_PAR) & (ub >= 0.0f) & (ub <= 1.0f) & (ua >= 0.0f);
        umin = fminf(umin, ok ? ua : INFINITY);
    }
    s_red[w][lane] = umin;
    __syncthreads();
    if (w == 0) {
        float m = fminf(fminf(s_red[0][lane], s_red[1][lane]),
                        fminf(s_red[2][lane], s_red[3][lane]));
        ws[sc * (NB * L_OBS) + b * L_OBS + beam] = m;
    }
}

__global__ void finalize_fb_kernel(const float4* __restrict__ seg,
                                   const float* __restrict__ pose,
                                   const float* __restrict__ part,
                                   float* __restrict__ out) {
    int t = blockIdx.x * blockDim.x + threadIdx.x;
    if (t >= NB * L_OBS) return;
    const int b    = t >> 9;
    const int beam = t & (L_OBS - 1);
    const float x1 = pose[b * 3 + 0];
    const float y1 = pose[b * 3 + 1];
    const float th = pose[b * 3 + 2];
    const float ang = (float)beam * ANG_STEP + th;
    const float rx = cosf(ang), ry = sinf(ang);
    float u = INFINITY;
    #pragma unroll
    for (int s = 0; s < SC; ++s) u = fminf(u, part[s * (NB * L_OBS) + t]);
    if (isinf(u)) {
        float4 s0 = seg[0];
        float sx = s0.z - s0.x, sy = s0.w - s0.y;
        float xd = x1 - s0.x,   yd = y1 - s0.y;
        float rxs   = sy * rx - sx * ry;
        float num_a = sx * yd - sy * xd;
        u = (fabsf(rxs) < EPS_PAR) ? 0.0f : (num_a / rxs);
    }
    float ix = x1 + rx * u;
    float iy = y1 + ry * u;
    float dx = ix - x1, dy = iy - y1;
    float c = cosf(th), s = sinf(th);
    out[t * 2 + 0] = ix;
    out[t * 2 + 1] = iy;
    const int off = NB * L_OBS * 2;
    out[off + t * 2 + 0] =  dx * c + dy * s;
    out[off + t * 2 + 1] = -dx * s + dy * c;
}

extern "C" void kernel_launch(void* const* d_in, const int* in_sizes, int n_in,
                              void* d_out, int out_size, void* d_ws, size_t ws_size,
                              hipStream_t stream) {
    const float4* seg  = (const float4*)d_in[0];   // (N,4) float32
    const float*  pose = (const float*)d_in[1];    // (B,3) float32
    float* out = (float*)d_out;

    if (ws_size >= (size_t)PART2_FLOATS * sizeof(float)) {
        float* part = (float*)d_ws;                // [SC2][NB*L_OBS]
        raycast6_kernel<<<1024, 256, 0, stream>>>(seg, pose, part);
        finalize6_kernel<<<16, 256, 0, stream>>>(seg, pose, part, out);
    } else {
        float* part = (float*)d_ws;                // [SC][NB*L_OBS]
        raycast_part_kernel<<<1024, 256, 0, stream>>>(seg, pose, part);
        finalize_fb_kernel<<<16, 256, 0, stream>>>(seg, pose, part, out);
    }
}

// Round 7
// 22.772 us; speedup vs baseline: 1.9789x; 1.2554x over previous
//
#include <hip/hip_runtime.h>
#include <math.h>

#define L_OBS   512
#define NSEG    8192
#define NB      8
#define EPS_PAR 1e-4f
#define ANG_STEP 0.012271846644580566f  // FOV / L_OBS

// Raycast (unchanged from R6): block = (b, beamgroup of 128, segchunk of 256).
// 4 waves; wave w owns segs [w*64, w*64+64); thread owns beams (bg*128+lane, +64).
// One ds_read_b128 per segment serves 128 tests.
#define SC2   32
#define CSEG2 (NSEG / SC2)               // 256 segs per block
#define PART2_FLOATS (SC2 * NB * L_OBS)  // 512 KB

__global__ __launch_bounds__(256) void raycast6_kernel(
    const float4* __restrict__ seg, const float* __restrict__ pose,
    float* __restrict__ part) {
    __shared__ float4 s4[CSEG2];     // {sx, sy, xd, yd}
    __shared__ float  s_red[4][128];

    const int gid = blockIdx.x;      // 1024 = 8b * 4bg * 32sc
    const int sc = gid & (SC2 - 1);
    const int bg = (gid >> 5) & 3;
    const int b  = gid >> 7;

    const float x1 = pose[b * 3 + 0];
    const float y1 = pose[b * 3 + 1];
    const float th = pose[b * 3 + 2];

    const int t = threadIdx.x;
    {
        float4 v = seg[sc * CSEG2 + t];
        s4[t] = make_float4(v.z - v.x, v.w - v.y, x1 - v.x, y1 - v.y);
    }

    const int lane = t & 63;
    const int w    = t >> 6;
    const int beam0 = bg * 128 + lane;
    const float a0 = (float)beam0 * ANG_STEP + th;
    const float a1 = (float)(beam0 + 64) * ANG_STEP + th;
    const float rx0 = cosf(a0), ry0 = sinf(a0);
    const float rx1 = cosf(a1), ry1 = sinf(a1);
    const float INF = __builtin_inff();
    __syncthreads();

    float u0 = INF, u1 = INF;
    const float4* __restrict__ p = &s4[w * 64];
    #pragma unroll 8
    for (int i = 0; i < 64; ++i) {
        float4 s = p[i];                  // broadcast b128 (only LDS op in loop)
        float na = s.x * s.w - s.y * s.z; // sx*yd - sy*xd

        float rxs0 = s.y * rx0 - s.x * ry0;
        float nb0  = rx0 * s.w - ry0 * s.z;
        float r0   = __builtin_amdgcn_rcpf(rxs0);
        float ua0  = na  * r0;
        float ub0  = nb0 * r0;
        bool ok0 = (fabsf(rxs0) >= EPS_PAR) & (ub0 >= 0.0f) & (ub0 <= 1.0f) & (ua0 >= 0.0f);
        u0 = fminf(u0, ok0 ? ua0 : INF);

        float rxs1 = s.y * rx1 - s.x * ry1;
        float nb1  = rx1 * s.w - ry1 * s.z;
        float r1   = __builtin_amdgcn_rcpf(rxs1);
        float ua1  = na  * r1;
        float ub1  = nb1 * r1;
        bool ok1 = (fabsf(rxs1) >= EPS_PAR) & (ub1 >= 0.0f) & (ub1 <= 1.0f) & (ua1 >= 0.0f);
        u1 = fminf(u1, ok1 ? ua1 : INF);
    }

    s_red[w][lane]      = u0;
    s_red[w][lane + 64] = u1;
    __syncthreads();
    if (t < 128) {
        float m = fminf(fminf(s_red[0][t], s_red[1][t]),
                        fminf(s_red[2][t], s_red[3][t]));
        part[sc * (NB * L_OBS) + b * L_OBS + bg * 128 + t] = m;
    }
}

// Parallel finalize: 64 blocks x 256 threads. Thread (q = t>>6, lane = t&63)
// reduces partial rows [q*8, q*8+8) for beam blk*64+lane (coalesced columns),
// 4-way LDS combine, wave 0 computes outputs. 16x the waves of the old
// finalize -> cross-XCD dirty-read latency covered by parallelism.
__global__ __launch_bounds__(256) void finalize7_kernel(
    const float4* __restrict__ seg, const float* __restrict__ pose,
    const float* __restrict__ part, float* __restrict__ out) {
    __shared__ float s_red[4][64];

    const int t    = threadIdx.x;
    const int lane = t & 63;
    const int q    = t >> 6;
    const int gbeam = blockIdx.x * 64 + lane;   // 64 blocks cover 4096 beam-slots

    float u = INFINITY;
    #pragma unroll
    for (int j = 0; j < 8; ++j)
        u = fminf(u, part[(q * 8 + j) * (NB * L_OBS) + gbeam]);

    s_red[q][lane] = u;
    __syncthreads();
    if (t < 64) {
        const int gb   = blockIdx.x * 64 + t;
        const int b    = gb >> 9;
        const int beam = gb & (L_OBS - 1);
        const float x1 = pose[b * 3 + 0];
        const float y1 = pose[b * 3 + 1];
        const float th = pose[b * 3 + 2];
        const float ang = (float)beam * ANG_STEP + th;
        const float rx = cosf(ang), ry = sinf(ang);

        float m = fminf(fminf(s_red[0][t], s_red[1][t]),
                        fminf(s_red[2][t], s_red[3][t]));

        if (isinf(m)) {
            // No valid intersection: ref takes u_a[0] (argmin of all-inf picks idx 0).
            float4 s0 = seg[0];
            float sx = s0.z - s0.x, sy = s0.w - s0.y;
            float xd = x1 - s0.x,   yd = y1 - s0.y;
            float rxs   = sy * rx - sx * ry;
            float num_a = sx * yd - sy * xd;
            m = (fabsf(rxs) < EPS_PAR) ? 0.0f : (num_a / rxs);
        }

        float ix = x1 + rx * m;
        float iy = y1 + ry * m;
        float dx = ix - x1, dy = iy - y1;
        float c = cosf(th), s = sinf(th);
        out[gb * 2 + 0] = ix;
        out[gb * 2 + 1] = iy;
        const int off = NB * L_OBS * 2;
        out[off + gb * 2 + 0] =  dx * c + dy * s;   // R = [[c,-s],[s,c]], out = d @ R
        out[off + gb * 2 + 1] = -dx * s + dy * c;
    }
}

// ---------------- fallback (R2, proven) if ws < 512 KB ----------------
#define SC      16
#define SEGS    (NSEG / SC)

__global__ __launch_bounds__(256) void raycast_part_kernel(
    const float4* __restrict__ seg, const float* __restrict__ pose,
    float* __restrict__ ws) {
    __shared__ float4 s4[SEGS];
    __shared__ float  sna[SEGS];
    __shared__ float  s_red[4][64];
    const int gid = blockIdx.x;
    const int sc = gid & (SC - 1);
    const int bg = (gid >> 4) & 7;
    const int b  = gid >> 7;
    const float x1 = pose[b * 3 + 0];
    const float y1 = pose[b * 3 + 1];
    const float th = pose[b * 3 + 2];
    const int tid = threadIdx.x;
    for (int i = tid; i < SEGS; i += 256) {
        float4 v = seg[sc * SEGS + i];
        float sx = v.z - v.x, sy = v.w - v.y;
        float xd = x1 - v.x, yd = y1 - v.y;
        s4[i]  = make_float4(sx, sy, xd, yd);
        sna[i] = sx * yd - sy * xd;
    }
    const int lane = tid & 63;
    const int w    = tid >> 6;
    const int beam = bg * 64 + lane;
    const float ang = (float)beam * ANG_STEP + th;
    const float rx = cosf(ang), ry = sinf(ang);
    __syncthreads();
    float umin = INFINITY;
    const float4* p  = &s4[w * 128];
    const float*  pn = &sna[w * 128];
    #pragma unroll 8
    for (int i = 0; i < 128; ++i) {
        float4 s = p[i];
        float na = pn[i];
        float rxs = s.y * rx - s.x * ry;
        float nb  = rx * s.w - ry * s.z;
        float r   = __builtin_amdgcn_rcpf(rxs);
        float ua  = na * r;
        float ub  = nb * r;
        bool ok = (fabsf(rxs) >= EPS_PAR) & (ub >= 0.0f) & (ub <= 1.0f) & (ua >= 0.0f);
        umin = fminf(umin, ok ? ua : INFINITY);
    }
    s_red[w][lane] = umin;
    __syncthreads();
    if (w == 0) {
        float m = fminf(fminf(s_red[0][lane], s_red[1][lane]),
                        fminf(s_red[2][lane], s_red[3][lane]));
        ws[sc * (NB * L_OBS) + b * L_OBS + beam] = m;
    }
}

__global__ void finalize_fb_kernel(const float4* __restrict__ seg,
                                   const float* __restrict__ pose,
                                   const float* __restrict__ part,
                                   float* __restrict__ out) {
    int t = blockIdx.x * blockDim.x + threadIdx.x;
    if (t >= NB * L_OBS) return;
    const int b    = t >> 9;
    const int beam = t & (L_OBS - 1);
    const float x1 = pose[b * 3 + 0];
    const float y1 = pose[b * 3 + 1];
    const float th = pose[b * 3 + 2];
    const float ang = (float)beam * ANG_STEP + th;
    const float rx = cosf(ang), ry = sinf(ang);
    float u = INFINITY;
    #pragma unroll
    for (int s = 0; s < SC; ++s) u = fminf(u, part[s * (NB * L_OBS) + t]);
    if (isinf(u)) {
        float4 s0 = seg[0];
        float sx = s0.z - s0.x, sy = s0.w - s0.y;
        float xd = x1 - s0.x,   yd = y1 - s0.y;
        float rxs   = sy * rx - sx * ry;
        float num_a = sx * yd - sy * xd;
        u = (fabsf(rxs) < EPS_PAR) ? 0.0f : (num_a / rxs);
    }
    float ix = x1 + rx * u;
    float iy = y1 + ry * u;
    float dx = ix - x1, dy = iy - y1;
    float c = cosf(th), s = sinf(th);
    out[t * 2 + 0] = ix;
    out[t * 2 + 1] = iy;
    const int off = NB * L_OBS * 2;
    out[off + t * 2 + 0] =  dx * c + dy * s;
    out[off + t * 2 + 1] = -dx * s + dy * c;
}

extern "C" void kernel_launch(void* const* d_in, const int* in_sizes, int n_in,
                              void* d_out, int out_size, void* d_ws, size_t ws_size,
                              hipStream_t stream) {
    const float4* seg  = (const float4*)d_in[0];   // (N,4) float32
    const float*  pose = (const float*)d_in[1];    // (B,3) float32
    float* out = (float*)d_out;

    if (ws_size >= (size_t)PART2_FLOATS * sizeof(float)) {
        float* part = (float*)d_ws;                // [SC2][NB*L_OBS]
        raycast6_kernel<<<1024, 256, 0, stream>>>(seg, pose, part);
        finalize7_kernel<<<64, 256, 0, stream>>>(seg, pose, part, out);
    } else {
        float* part = (float*)d_ws;                // [SC][NB*L_OBS]
        raycast_part_kernel<<<1024, 256, 0, stream>>>(seg, pose, part);
        finalize_fb_kernel<<<16, 256, 0, stream>>>(seg, pose, part, out);
    }
}

// Round 8
// 21.238 us; speedup vs baseline: 2.1218x; 1.0722x over previous
//
#include <hip/hip_runtime.h>
#include <math.h>

#define L_OBS   512
#define NSEG    8192
#define NB      8
#define EPS_PAR 1e-4f
#define ANG_STEP 0.012271846644580566f  // FOV / L_OBS

// Raycast: block = (b, beamgroup of 128, segchunk of 256), 512 threads (8 waves).
// Wave w owns segs [w*32, w*32+32); thread owns beams (bg*128+lane, +64): 64 tests.
// vs R7: same grid, same per-block work, same partials — only waves/SIMD doubled
// (4 -> 8) to fill VALU issue bubbles (rcp latency, lgkm waits).
#define SC2   32
#define CSEG2 (NSEG / SC2)               // 256 segs per block
#define PART2_FLOATS (SC2 * NB * L_OBS)  // 512 KB

__global__ __launch_bounds__(512) void raycast8_kernel(
    const float4* __restrict__ seg, const float* __restrict__ pose,
    float* __restrict__ part) {
    __shared__ float4 s4[CSEG2];     // {sx, sy, xd, yd}
    __shared__ float  s_red[8][128];

    const int gid = blockIdx.x;      // 1024 = 8b * 4bg * 32sc
    const int sc = gid & (SC2 - 1);
    const int bg = (gid >> 5) & 3;
    const int b  = gid >> 7;

    const float x1 = pose[b * 3 + 0];
    const float y1 = pose[b * 3 + 1];
    const float th = pose[b * 3 + 2];

    const int t = threadIdx.x;
    if (t < CSEG2) {
        float4 v = seg[sc * CSEG2 + t];
        s4[t] = make_float4(v.z - v.x, v.w - v.y, x1 - v.x, y1 - v.y);
    }

    const int lane = t & 63;
    const int w    = t >> 6;         // 0..7
    const int beam0 = bg * 128 + lane;
    const float a0 = (float)beam0 * ANG_STEP + th;
    const float a1 = (float)(beam0 + 64) * ANG_STEP + th;
    const float rx0 = cosf(a0), ry0 = sinf(a0);
    const float rx1 = cosf(a1), ry1 = sinf(a1);
    const float INF = __builtin_inff();
    __syncthreads();

    float u0 = INF, u1 = INF;
    const float4* __restrict__ p = &s4[w * 32];
    #pragma unroll 8
    for (int i = 0; i < 32; ++i) {
        float4 s = p[i];                  // broadcast b128 (only LDS op in loop)
        float na = s.x * s.w - s.y * s.z; // sx*yd - sy*xd

        float rxs0 = s.y * rx0 - s.x * ry0;
        float nb0  = rx0 * s.w - ry0 * s.z;
        float r0   = __builtin_amdgcn_rcpf(rxs0);
        float ua0  = na  * r0;
        float ub0  = nb0 * r0;
        bool ok0 = (fabsf(rxs0) >= EPS_PAR) & (ub0 >= 0.0f) & (ub0 <= 1.0f) & (ua0 >= 0.0f);
        u0 = fminf(u0, ok0 ? ua0 : INF);

        float rxs1 = s.y * rx1 - s.x * ry1;
        float nb1  = rx1 * s.w - ry1 * s.z;
        float r1   = __builtin_amdgcn_rcpf(rxs1);
        float ua1  = na  * r1;
        float ub1  = nb1 * r1;
        bool ok1 = (fabsf(rxs1) >= EPS_PAR) & (ub1 >= 0.0f) & (ub1 <= 1.0f) & (ua1 >= 0.0f);
        u1 = fminf(u1, ok1 ? ua1 : INF);
    }

    s_red[w][lane]      = u0;
    s_red[w][lane + 64] = u1;
    __syncthreads();
    if (t < 128) {
        float m0 = fminf(fminf(s_red[0][t], s_red[1][t]),
                         fminf(s_red[2][t], s_red[3][t]));
        float m1 = fminf(fminf(s_red[4][t], s_red[5][t]),
                         fminf(s_red[6][t], s_red[7][t]));
        part[sc * (NB * L_OBS) + b * L_OBS + bg * 128 + t] = fminf(m0, m1);
    }
}

// Parallel finalize (unchanged from R7): 64 blocks x 256 threads.
__global__ __launch_bounds__(256) void finalize7_kernel(
    const float4* __restrict__ seg, const float* __restrict__ pose,
    const float* __restrict__ part, float* __restrict__ out) {
    __shared__ float s_red[4][64];

    const int t    = threadIdx.x;
    const int lane = t & 63;
    const int q    = t >> 6;
    const int gbeam = blockIdx.x * 64 + lane;   // 64 blocks cover 4096 beam-slots

    float u = INFINITY;
    #pragma unroll
    for (int j = 0; j < 8; ++j)
        u = fminf(u, part[(q * 8 + j) * (NB * L_OBS) + gbeam]);

    s_red[q][lane] = u;
    __syncthreads();
    if (t < 64) {
        const int gb   = blockIdx.x * 64 + t;
        const int b    = gb >> 9;
        const int beam = gb & (L_OBS - 1);
        const float x1 = pose[b * 3 + 0];
        const float y1 = pose[b * 3 + 1];
        const float th = pose[b * 3 + 2];
        const float ang = (float)beam * ANG_STEP + th;
        const float rx = cosf(ang), ry = sinf(ang);

        float m = fminf(fminf(s_red[0][t], s_red[1][t]),
                        fminf(s_red[2][t], s_red[3][t]));

        if (isinf(m)) {
            // No valid intersection: ref takes u_a[0] (argmin of all-inf picks idx 0).
            float4 s0 = seg[0];
            float sx = s0.z - s0.x, sy = s0.w - s0.y;
            float xd = x1 - s0.x,   yd = y1 - s0.y;
            float rxs   = sy * rx - sx * ry;
            float num_a = sx * yd - sy * xd;
            m = (fabsf(rxs) < EPS_PAR) ? 0.0f : (num_a / rxs);
        }

        float ix = x1 + rx * m;
        float iy = y1 + ry * m;
        float dx = ix - x1, dy = iy - y1;
        float c = cosf(th), s = sinf(th);
        out[gb * 2 + 0] = ix;
        out[gb * 2 + 1] = iy;
        const int off = NB * L_OBS * 2;
        out[off + gb * 2 + 0] =  dx * c + dy * s;   // R = [[c,-s],[s,c]], out = d @ R
        out[off + gb * 2 + 1] = -dx * s + dy * c;
    }
}

extern "C" void kernel_launch(void* const* d_in, const int* in_sizes, int n_in,
                              void* d_out, int out_size, void* d_ws, size_t ws_size,
                              hipStream_t stream) {
    const float4* seg  = (const float4*)d_in[0];   // (N,4) float32
    const float*  pose = (const float*)d_in[1];    // (B,3) float32
    float* out = (float*)d_out;
    float* part = (float*)d_ws;                    // [SC2][NB*L_OBS], 512 KB (ws >= 2MB proven in R5)

    raycast8_kernel<<<1024, 512, 0, stream>>>(seg, pose, part);
    finalize7_kernel<<<64, 256, 0, stream>>>(seg, pose, part, out);
}